// Round 12
// baseline (66.392 us; speedup 1.0000x reference)
//
#include <hip/hip_runtime.h>

#define B_N    1024
#define F_DIMC 768
#define M_DIM  512
#define C_N    100
#define KHALF  (F_DIMC / 2)     // 384 per K-split half
#define NT2    (KHALF / 32)     // 12 k-steps of BK=32
#define NGEMM  512              // 256 tiles x 2 K-halves
#define NIDX   25               // 25 blocks x 4 waves = 100 classes

typedef float f32x4v __attribute__((ext_vector_type(4)));
typedef short s16x8  __attribute__((ext_vector_type(8)));

__device__ __forceinline__ unsigned int f2bf_bits(float x) {
  // RNE f32 -> bf16 bits (inputs finite, post-relu)
  unsigned int u = __builtin_bit_cast(unsigned int, x);
  return (u + 0x7fffu + ((u >> 16) & 1u)) >> 16;
}

// ---------------------------------------------------------------------------
// Kernel 1 (R8 verbatim): partial GEMM (K-split x2, no relu) + index build.
// ---------------------------------------------------------------------------
__global__ __launch_bounds__(256) void gemm_index_kernel(
    const float* __restrict__ X, const float* __restrict__ W,
    const int* __restrict__ labels, float* __restrict__ part,
    int* __restrict__ counts, int* __restrict__ idx) {
  __shared__ float As[2][32][36];
  __shared__ float Bs[2][32][64];
  __shared__ int   lab[B_N];

  const int t = threadIdx.x;

  if (blockIdx.x >= NGEMM) {  // ---- index path ----
    for (int i = t; i < B_N; i += 256) lab[i] = labels[i];
    __syncthreads();
    const int w    = t >> 6;
    const int lane = t & 63;
    const int c    = ((int)blockIdx.x - NGEMM) * 4 + w;
    if (c < C_N) {
      int base = 0;
      for (int ch = 0; ch < 16; ++ch) {
        const int j = ch * 64 + lane;
        const bool hit = (lab[j] == c);
        const unsigned long long mask = __ballot(hit);
        if (hit) {
          const int r = __popcll(mask & ((1ull << lane) - 1ull));
          idx[c * B_N + base + r] = j;
        }
        base += __popcll(mask);
      }
      if (lane == 0) counts[c] = base;
    }
    return;
  }

  // ---- GEMM path ----
  const int kb   = (int)blockIdx.x >> 8;
  const int tile = (int)blockIdx.x & 255;
  const int bm = (tile >> 3) * 32;
  const int bn = (tile & 7) * 64;
  const int tx = t & 15;
  const int ty = t >> 4;

  const int ar  = t >> 3;
  const int akq = (t & 7) * 4;
  const int bk0 = t >> 4;
  const int bk1 = bk0 + 16;
  const int bnq = (t & 15) * 4;

  const float* __restrict__ Arow =
      X + (size_t)(bm + ar) * F_DIMC + kb * KHALF + akq;
  const float* __restrict__ Bcol =
      W + (size_t)kb * KHALF * M_DIM + bn + bnq;

  float4 pa  = *(const float4*)(Arow);
  float4 pb0 = *(const float4*)(Bcol + (size_t)bk0 * M_DIM);
  float4 pb1 = *(const float4*)(Bcol + (size_t)bk1 * M_DIM);

  float acc[2][4] = {};

  As[0][akq + 0][ar] = pa.x;
  As[0][akq + 1][ar] = pa.y;
  As[0][akq + 2][ar] = pa.z;
  As[0][akq + 3][ar] = pa.w;
  *(float4*)&Bs[0][bk0][bnq] = pb0;
  *(float4*)&Bs[0][bk1][bnq] = pb1;
  __syncthreads();

  for (int it = 0; it < NT2; ++it) {
    const int cur = it & 1;
    if (it + 1 < NT2) {
      const int k0 = (it + 1) * 32;
      pa  = *(const float4*)(Arow + k0);
      pb0 = *(const float4*)(Bcol + (size_t)(k0 + bk0) * M_DIM);
      pb1 = *(const float4*)(Bcol + (size_t)(k0 + bk1) * M_DIM);
    }
#pragma unroll
    for (int kk = 0; kk < 32; ++kk) {
      float2 av = *(const float2*)&As[cur][kk][ty * 2];
      float4 bv = *(const float4*)&Bs[cur][kk][tx * 4];
      acc[0][0] += av.x * bv.x;
      acc[0][1] += av.x * bv.y;
      acc[0][2] += av.x * bv.z;
      acc[0][3] += av.x * bv.w;
      acc[1][0] += av.y * bv.x;
      acc[1][1] += av.y * bv.y;
      acc[1][2] += av.y * bv.z;
      acc[1][3] += av.y * bv.w;
    }
    if (it + 1 < NT2) {
      const int nxt = cur ^ 1;
      As[nxt][akq + 0][ar] = pa.x;
      As[nxt][akq + 1][ar] = pa.y;
      As[nxt][akq + 2][ar] = pa.z;
      As[nxt][akq + 3][ar] = pa.w;
      *(float4*)&Bs[nxt][bk0][bnq] = pb0;
      *(float4*)&Bs[nxt][bk1][bnq] = pb1;
    }
    __syncthreads();
  }

  float* __restrict__ dst = part + (size_t)kb * B_N * M_DIM;
#pragma unroll
  for (int j = 0; j < 2; ++j) {
    float4 o = make_float4(acc[j][0], acc[j][1], acc[j][2], acc[j][3]);
    *(float4*)&dst[(size_t)(bm + ty * 2 + j) * M_DIM + bn + tx * 4] = o;
  }
}

// ---------------------------------------------------------------------------
// Kernel 2: phi via MFMA (16x16x32 bf16), mu/count fp32.
// grid = (17, C) x 256 thr. x<16: 32-row x 512-col panel of phi[c];
// x==16: mu/count.
// Staging: feat_c^T as bf16 in LDS Ft[512 cols][40] (80 B padded rows,
// 32 sample slots, zero-padded past n). A/B fragments are identical-shaped
// ds_read_b128: lane&15 -> row/col, (lane>>4)*8 -> k-quad. One MFMA per
// 16x16 tile covers K=32. Stores: f32 scalar, 64 B segments, 64/thread.
// ---------------------------------------------------------------------------
__global__ __launch_bounds__(256, 4) void phi_mu_kernel(
    const float* __restrict__ p0, const float* __restrict__ p1,
    const int* __restrict__ counts, const int* __restrict__ idx,
    float* __restrict__ phi, float* __restrict__ mu,
    float* __restrict__ cnt_out) {
  const int c = blockIdx.y;
  const int n = counts[c];
  const int* __restrict__ id = idx + c * B_N;
  const int t = threadIdx.x;

  if (blockIdx.x == 16) {  // ---- mu / count path (fp32 exact) ----
    float2 acc = make_float2(0.f, 0.f);
    for (int s = 0; s < n; ++s) {
      const size_t o = (size_t)id[s] * M_DIM + t * 2;
      const float2 q0 = *(const float2*)&p0[o];
      const float2 q1 = *(const float2*)&p1[o];
      acc.x += fmaxf(q0.x + q1.x, 0.f);
      acc.y += fmaxf(q0.y + q1.y, 0.f);
    }
    *(float2*)&mu[(size_t)c * M_DIM + t * 2] = acc;
    if (t == 0) cnt_out[c] = (float)n;
    return;
  }

  // ---- phi MFMA panel: rows px*32..+32, all 512 cols ----
  const int px   = (int)blockIdx.x;  // 0..15
  const int lane = t & 63;
  const int w    = t >> 6;           // wave 0..3 -> col-tiles 8w..8w+7

  __shared__ __align__(16) unsigned short Ft[M_DIM][40];  // 80 B rows, 40 KB

  const int m0 = px * 32;      // panel row base
  const int n0 = w * 128;      // wave col base
  const int fr = lane & 15;    // fragment row/col within tile
  const int fq = (lane >> 4) * 8;  // k-quad offset (8 bf16 = 16 B)

  f32x4v acc[2][8] = {};       // [row-tile][col-tile]

  for (int s0 = 0; s0 < n; s0 += 32) {
    if (s0) __syncthreads();
    // stage 512 cols x 16 sample-pairs (8192 u32) by 256 threads: 32 iters
#pragma unroll 4
    for (int i = 0; i < 32; ++i) {
      const int v   = t + (i << 8);
      const int col = v & 511;
      const int j   = v >> 9;        // pair 0..15
      const int sA  = s0 + 2 * j;
      float fa = 0.f, fb = 0.f;
      if (sA < n) {
        const size_t o = (size_t)id[sA] * M_DIM + col;
        fa = fmaxf(p0[o] + p1[o], 0.f);
      }
      if (sA + 1 < n) {
        const size_t o = (size_t)id[sA + 1] * M_DIM + col;
        fb = fmaxf(p0[o] + p1[o], 0.f);
      }
      *(unsigned int*)&Ft[col][2 * j] =
          f2bf_bits(fa) | (f2bf_bits(fb) << 16);
    }
    __syncthreads();

    s16x8 bfr[8];
#pragma unroll
    for (int ct = 0; ct < 8; ++ct)
      bfr[ct] = *(const s16x8*)&Ft[n0 + ct * 16 + fr][fq];
#pragma unroll
    for (int rt = 0; rt < 2; ++rt) {
      const s16x8 af = *(const s16x8*)&Ft[m0 + rt * 16 + fr][fq];
#pragma unroll
      for (int ct = 0; ct < 8; ++ct)
        acc[rt][ct] = __builtin_amdgcn_mfma_f32_16x16x32_bf16(
            af, bfr[ct], acc[rt][ct], 0, 0, 0);
    }
  }

  // store: row = m0 + rt*16 + (lane>>4)*4 + r ; col = n0 + ct*16 + fr
  float* __restrict__ out = phi + (size_t)c * M_DIM * M_DIM;
#pragma unroll
  for (int rt = 0; rt < 2; ++rt) {
    const int rbase = m0 + rt * 16 + (lane >> 4) * 4;
#pragma unroll
    for (int r = 0; r < 4; ++r) {
      const size_t row = (size_t)(rbase + r) * M_DIM;
#pragma unroll
      for (int ct = 0; ct < 8; ++ct)
        out[row + n0 + ct * 16 + fr] = acc[rt][ct][r];
    }
  }
}

// ---------------------------------------------------------------------------
extern "C" void kernel_launch(void* const* d_in, const int* in_sizes, int n_in,
                              void* d_out, int out_size, void* d_ws,
                              size_t ws_size, hipStream_t stream) {
  const float* X      = (const float*)d_in[0];
  const float* W      = (const float*)d_in[1];
  const int*   labels = (const int*)d_in[2];

  float* out = (float*)d_out;
  float* phi = out;                                // C*M*M
  float* mu  = out + (size_t)C_N * M_DIM * M_DIM;  // C*M
  float* cnt = mu + (size_t)C_N * M_DIM;           // C

  float* part   = (float*)d_ws;                    // 2 x B*M fp32 = 4 MB
  int*   counts = (int*)((char*)d_ws + (size_t)2 * B_N * M_DIM * sizeof(float));
  int*   idx    = counts + 128;                    // C*B ints

  hipLaunchKernelGGL(gemm_index_kernel, dim3(NGEMM + NIDX), dim3(256), 0,
                     stream, X, W, labels, part, counts, idx);
  hipLaunchKernelGGL(phi_mu_kernel, dim3(17, C_N), dim3(256), 0, stream,
                     part, part + (size_t)B_N * M_DIM, counts, idx,
                     phi, mu, cnt);
}

// Round 14
// 47.097 us; speedup vs baseline: 1.4097x; 1.4097x over previous
//
#include <hip/hip_runtime.h>
#include <hip/hip_cooperative_groups.h>

namespace cg = cooperative_groups;

#define B_N    1024
#define F_DIMC 768
#define M_DIM  512
#define C_N    100
#define KHALF  (F_DIMC / 2)     // 384 per K-split half
#define NT2    (KHALF / 32)     // 12 k-steps of BK=32
#define NGEMM  512              // 256 tiles x 2 K-halves
#define NIDX   25               // 25 blocks x 4 waves = 100 classes
#define GRID_N 512              // 2 blocks/CU guaranteed co-resident
#define NUNITS (17 * C_N)       // 1700 phase-2 units

typedef float f32x4 __attribute__((ext_vector_type(4)));

union SMem {  // max(29696, 32768) = 32768 B
  struct {
    float As[2][32][36];
    float Bs[2][32][64];
    int   lab[B_N];
  } g;
  float F[16][M_DIM];
};

// ---------------------------------------------------------------------------
// Shared device bodies (used by both fused and fallback kernels).
// ---------------------------------------------------------------------------
__device__ __forceinline__ void gemm_unit(
    int b, int t, const float* __restrict__ X, const float* __restrict__ W,
    float* __restrict__ part, float As[2][32][36], float Bs[2][32][64]) {
  const int kb   = b >> 8;
  const int tile = b & 255;
  const int bm = (tile >> 3) * 32;
  const int bn = (tile & 7) * 64;
  const int tx = t & 15;
  const int ty = t >> 4;

  const int ar  = t >> 3;
  const int akq = (t & 7) * 4;
  const int bk0 = t >> 4;
  const int bk1 = bk0 + 16;
  const int bnq = (t & 15) * 4;

  const float* __restrict__ Arow =
      X + (size_t)(bm + ar) * F_DIMC + kb * KHALF + akq;
  const float* __restrict__ Bcol =
      W + (size_t)kb * KHALF * M_DIM + bn + bnq;

  float4 pa  = *(const float4*)(Arow);
  float4 pb0 = *(const float4*)(Bcol + (size_t)bk0 * M_DIM);
  float4 pb1 = *(const float4*)(Bcol + (size_t)bk1 * M_DIM);

  float acc[2][4] = {};

  As[0][akq + 0][ar] = pa.x;
  As[0][akq + 1][ar] = pa.y;
  As[0][akq + 2][ar] = pa.z;
  As[0][akq + 3][ar] = pa.w;
  *(float4*)&Bs[0][bk0][bnq] = pb0;
  *(float4*)&Bs[0][bk1][bnq] = pb1;
  __syncthreads();

  for (int it = 0; it < NT2; ++it) {
    const int cur = it & 1;
    if (it + 1 < NT2) {
      const int k0 = (it + 1) * 32;
      pa  = *(const float4*)(Arow + k0);
      pb0 = *(const float4*)(Bcol + (size_t)(k0 + bk0) * M_DIM);
      pb1 = *(const float4*)(Bcol + (size_t)(k0 + bk1) * M_DIM);
    }
#pragma unroll
    for (int kk = 0; kk < 32; ++kk) {
      float2 av = *(const float2*)&As[cur][kk][ty * 2];
      float4 bv = *(const float4*)&Bs[cur][kk][tx * 4];
      acc[0][0] += av.x * bv.x;
      acc[0][1] += av.x * bv.y;
      acc[0][2] += av.x * bv.z;
      acc[0][3] += av.x * bv.w;
      acc[1][0] += av.y * bv.x;
      acc[1][1] += av.y * bv.y;
      acc[1][2] += av.y * bv.z;
      acc[1][3] += av.y * bv.w;
    }
    if (it + 1 < NT2) {
      const int nxt = cur ^ 1;
      As[nxt][akq + 0][ar] = pa.x;
      As[nxt][akq + 1][ar] = pa.y;
      As[nxt][akq + 2][ar] = pa.z;
      As[nxt][akq + 3][ar] = pa.w;
      *(float4*)&Bs[nxt][bk0][bnq] = pb0;
      *(float4*)&Bs[nxt][bk1][bnq] = pb1;
    }
    __syncthreads();
  }

  float* __restrict__ dst = part + (size_t)kb * B_N * M_DIM;
#pragma unroll
  for (int j = 0; j < 2; ++j) {
    float4 o = make_float4(acc[j][0], acc[j][1], acc[j][2], acc[j][3]);
    *(float4*)&dst[(size_t)(bm + ty * 2 + j) * M_DIM + bn + tx * 4] = o;
  }
}

__device__ __forceinline__ void index_unit(
    int ib, int t, const int* __restrict__ labels, int* __restrict__ counts,
    int* __restrict__ idx, int lab[B_N]) {
  for (int i = t; i < B_N; i += 256) lab[i] = labels[i];
  __syncthreads();
  const int w    = t >> 6;
  const int lane = t & 63;
  const int c    = ib * 4 + w;
  if (c < C_N) {
    int base = 0;
    for (int ch = 0; ch < 16; ++ch) {
      const int j = ch * 64 + lane;
      const bool hit = (lab[j] == c);
      const unsigned long long mask = __ballot(hit);
      if (hit) {
        const int r = __popcll(mask & ((1ull << lane) - 1ull));
        idx[c * B_N + base + r] = j;
      }
      base += __popcll(mask);
    }
    if (lane == 0) counts[c] = base;
  }
  __syncthreads();
}

__device__ __forceinline__ void phimu_unit(
    int u, int t, const float* __restrict__ p0, const float* __restrict__ p1,
    const int* __restrict__ counts, const int* __restrict__ idx,
    float* __restrict__ phi, float* __restrict__ mu,
    float* __restrict__ cnt_out, float F[16][M_DIM]) {
  const int c   = u / 17;
  const int sub = u - c * 17;
  const int n = counts[c];
  const int* __restrict__ id = idx + c * B_N;

  if (sub == 16) {  // ---- mu / count ----
    float2 acc = make_float2(0.f, 0.f);
    for (int s = 0; s < n; ++s) {
      const size_t o = (size_t)id[s] * M_DIM + t * 2;
      const float2 q0 = *(const float2*)&p0[o];
      const float2 q1 = *(const float2*)&p1[o];
      acc.x += fmaxf(q0.x + q1.x, 0.f);
      acc.y += fmaxf(q0.y + q1.y, 0.f);
    }
    *(float2*)&mu[(size_t)c * M_DIM + t * 2] = acc;
    if (t == 0) cnt_out[c] = (float)n;
    return;
  }

  const int px = sub;       // 0..15
  const int tr = t >> 6;
  const int tc = t & 63;

  float acc[8][8] = {};

  for (int s0 = 0; s0 < n; s0 += 16) {
    const int chunk  = min(16, n - s0);
    __syncthreads();                 // protect F before overwrite
    const int nslots = chunk << 7;
    for (int v = t; v < nslots; v += 256) {
      const int sl   = v >> 7;
      const int fp   = (v & 127) << 2;
      const size_t o = (size_t)id[s0 + sl] * M_DIM + fp;
      const float4 q0 = *(const float4*)&p0[o];
      const float4 q1 = *(const float4*)&p1[o];
      float4 f;
      f.x = fmaxf(q0.x + q1.x, 0.f);
      f.y = fmaxf(q0.y + q1.y, 0.f);
      f.z = fmaxf(q0.z + q1.z, 0.f);
      f.w = fmaxf(q0.w + q1.w, 0.f);
      *(float4*)&F[sl][fp] = f;
    }
    __syncthreads();
    for (int sl = 0; sl < chunk; ++sl) {
      const float4 a0 = *(const float4*)&F[sl][px * 32 + tr * 8];
      const float4 a1 = *(const float4*)&F[sl][px * 32 + tr * 8 + 4];
      const float4 b0 = *(const float4*)&F[sl][tc * 4];
      const float4 b1 = *(const float4*)&F[sl][256 + tc * 4];
      const float av[8] = {a0.x, a0.y, a0.z, a0.w, a1.x, a1.y, a1.z, a1.w};
      const float bv[8] = {b0.x, b0.y, b0.z, b0.w, b1.x, b1.y, b1.z, b1.w};
#pragma unroll
      for (int r = 0; r < 8; ++r)
#pragma unroll
        for (int q = 0; q < 8; ++q)
          acc[r][q] += av[r] * bv[q];
    }
  }

  float* __restrict__ out = phi + (size_t)c * M_DIM * M_DIM;
#pragma unroll
  for (int r = 0; r < 8; ++r) {
    const size_t row = (size_t)(px * 32 + tr * 8 + r) * M_DIM;
    const f32x4 o0 = {acc[r][0], acc[r][1], acc[r][2], acc[r][3]};
    const f32x4 o1 = {acc[r][4], acc[r][5], acc[r][6], acc[r][7]};
    __builtin_nontemporal_store(o0, (f32x4*)&out[row + tc * 4]);
    __builtin_nontemporal_store(o1, (f32x4*)&out[row + 256 + tc * 4]);
  }
}

// ---------------------------------------------------------------------------
// Fused cooperative kernel: 512 blocks, 2/CU guaranteed.
// ---------------------------------------------------------------------------
__global__ __launch_bounds__(256, 2) void fused_kernel(
    const float* __restrict__ X, const float* __restrict__ W,
    const int* __restrict__ labels, float* __restrict__ part,
    int* __restrict__ counts, int* __restrict__ idx,
    float* __restrict__ phi, float* __restrict__ mu,
    float* __restrict__ cnt_out) {
  __shared__ SMem sm;
  const int t = threadIdx.x;
  const int b = (int)blockIdx.x;

  for (int v = b; v < NGEMM + NIDX; v += GRID_N) {
    if (v < NGEMM)
      gemm_unit(v, t, X, W, part, sm.g.As, sm.g.Bs);
    else
      index_unit(v - NGEMM, t, labels, counts, idx, sm.g.lab);
  }

  cg::this_grid().sync();

  const float* p0 = part;
  const float* p1 = part + (size_t)B_N * M_DIM;
  for (int u = b; u < NUNITS; u += GRID_N)
    phimu_unit(u, t, p0, p1, counts, idx, phi, mu, cnt_out, sm.F);
}

// ---------------------------------------------------------------------------
// Fallback kernels (R8 two-kernel path).
// ---------------------------------------------------------------------------
__global__ __launch_bounds__(256) void gemm_index_kernel(
    const float* __restrict__ X, const float* __restrict__ W,
    const int* __restrict__ labels, float* __restrict__ part,
    int* __restrict__ counts, int* __restrict__ idx) {
  __shared__ SMem sm;
  const int t = threadIdx.x;
  if (blockIdx.x >= NGEMM)
    index_unit((int)blockIdx.x - NGEMM, t, labels, counts, idx, sm.g.lab);
  else
    gemm_unit((int)blockIdx.x, t, X, W, part, sm.g.As, sm.g.Bs);
}

__global__ __launch_bounds__(256, 4) void phi_mu_kernel(
    const float* __restrict__ p0, const float* __restrict__ p1,
    const int* __restrict__ counts, const int* __restrict__ idx,
    float* __restrict__ phi, float* __restrict__ mu,
    float* __restrict__ cnt_out) {
  __shared__ float F[16][M_DIM];
  const int u = (int)blockIdx.y * 17 + (int)blockIdx.x;
  phimu_unit(u, (int)threadIdx.x, p0, p1, counts, idx, phi, mu, cnt_out, F);
}

// ---------------------------------------------------------------------------
extern "C" void kernel_launch(void* const* d_in, const int* in_sizes, int n_in,
                              void* d_out, int out_size, void* d_ws,
                              size_t ws_size, hipStream_t stream) {
  const float* X      = (const float*)d_in[0];
  const float* W      = (const float*)d_in[1];
  const int*   labels = (const int*)d_in[2];

  float* out = (float*)d_out;
  float* phi = out;                                // C*M*M
  float* mu  = out + (size_t)C_N * M_DIM * M_DIM;  // C*M
  float* cnt = mu + (size_t)C_N * M_DIM;           // C

  float* part   = (float*)d_ws;                    // 2 x B*M fp32 = 4 MB
  int*   counts = (int*)((char*)d_ws + (size_t)2 * B_N * M_DIM * sizeof(float));
  int*   idx    = counts + 128;                    // C*B ints
  float* p1     = part + (size_t)B_N * M_DIM;

  int maxPerCU = 0;
  hipError_t qerr = hipOccupancyMaxActiveBlocksPerMultiprocessor(
      &maxPerCU, fused_kernel, 256, 0);

  if (qerr == hipSuccess && maxPerCU * 256 >= GRID_N) {
    void* args[] = {(void*)&X,    (void*)&W,      (void*)&labels,
                    (void*)&part, (void*)&counts, (void*)&idx,
                    (void*)&phi,  (void*)&mu,     (void*)&cnt};
    hipError_t lerr = hipLaunchCooperativeKernel(
        (const void*)fused_kernel, dim3(GRID_N), dim3(256), args, 0, stream);
    if (lerr == hipSuccess) return;
  }

  // Fallback: R8 two-kernel path.
  hipLaunchKernelGGL(gemm_index_kernel, dim3(NGEMM + NIDX), dim3(256), 0,
                     stream, X, W, labels, part, counts, idx);
  hipLaunchKernelGGL(phi_mu_kernel, dim3(17, C_N), dim3(256), 0, stream,
                     part, p1, counts, idx, phi, mu, cnt);
}

// Round 15
// 42.692 us; speedup vs baseline: 1.5551x; 1.1032x over previous
//
#include <hip/hip_runtime.h>

#define B_N    1024
#define F_DIMC 768
#define M_DIM  512
#define C_N    100
#define KSTEP  32
#define NSTEP  (F_DIMC / KSTEP)   // 24 k-steps
#define NGEMM  512                // 32 row-tiles x 16 col-tiles (32x32 out)
#define NIDX   25                 // 25 blocks x 4 waves = 100 classes

typedef float f32x4 __attribute__((ext_vector_type(4)));
typedef short s16x8 __attribute__((ext_vector_type(8)));

__device__ __forceinline__ unsigned int f2bf(float x) {
  // RNE f32 -> bf16 bits (finite inputs)
  unsigned int u = __builtin_bit_cast(unsigned int, x);
  return (u + 0x7fffu + ((u >> 16) & 1u)) >> 16;
}
__device__ __forceinline__ float bf2f(unsigned int h) {
  return __builtin_bit_cast(float, h << 16);
}

// ---------------------------------------------------------------------------
// Kernel 1: MFMA gemm feat = relu(X @ W) (split-bf16, 3-term) + index build.
// blocks 0..511: 32x32 output tile, full K=768, dbuf LDS, 4 waves (1 MFMA
//   subtile each). A stored [row][k] bf16 hi/lo; B stored [col][k] (transposed
//   in staging). Fragment patterns = R12-verified.
// blocks 512..536: ballot-rank index build (one wave per class).
// ---------------------------------------------------------------------------
__global__ __launch_bounds__(256) void gemm_index_kernel(
    const float* __restrict__ X, const float* __restrict__ W,
    const int* __restrict__ labels, float* __restrict__ feat,
    int* __restrict__ counts, int* __restrict__ idx) {
  __shared__ unsigned short Ah[2][32][40], Al[2][32][40];  // [row][k] pitch 80B
  __shared__ unsigned short Bh[2][32][40], Bl[2][32][40];  // [col][k] pitch 80B
  __shared__ int lab[B_N];

  const int t = threadIdx.x;
  const int b = (int)blockIdx.x;

  if (b >= NGEMM) {  // ---- index path ----
    for (int i = t; i < B_N; i += 256) lab[i] = labels[i];
    __syncthreads();
    const int w    = t >> 6;
    const int lane = t & 63;
    const int c    = (b - NGEMM) * 4 + w;
    if (c < C_N) {
      int base = 0;
      for (int ch = 0; ch < 16; ++ch) {
        const int j = ch * 64 + lane;
        const bool hit = (lab[j] == c);
        const unsigned long long mask = __ballot(hit);
        if (hit) {
          const int r = __popcll(mask & ((1ull << lane) - 1ull));
          idx[c * B_N + base + r] = j;
        }
        base += __popcll(mask);
      }
      if (lane == 0) counts[c] = base;
    }
    return;
  }

  // ---- MFMA gemm path ----
  const int bm = (b >> 4) * 32;   // 32 row tiles
  const int bn = (b & 15) * 32;   // 16 col tiles

  // staging roles: waves 0,1 stage X (8 elems/thread); waves 2,3 stage W.
  const bool isX = (t < 128);
  const int xr = t >> 2;              // 0..31 row
  const int xk = (t & 3) * 8;         // 0,8,16,24 k-offset
  const int uu = isX ? 0 : (t - 128);
  const int wk = (uu >> 3) * 2;       // 0..30 even k
  const int wc = (uu & 7) * 4;        // 0..28 col base

  const float* __restrict__ Xp = X + (size_t)(bm + xr) * F_DIMC + xk;
  const float* __restrict__ Wp = W + (size_t)wk * M_DIM + bn + wc;

  // compute roles: wave wv owns 16x16 subtile (m0, n0)
  const int lane = t & 63;
  const int wv   = t >> 6;
  const int m0 = (wv & 1) * 16;
  const int n0 = (wv >> 1) * 16;
  const int fr = lane & 15;
  const int fq = (lane >> 4) * 8;

  f32x4 acc = {0.f, 0.f, 0.f, 0.f};

  float4 ra0, ra1, rb0, rb1;
  if (isX) {
    ra0 = *(const float4*)(Xp);
    ra1 = *(const float4*)(Xp + 4);
  } else {
    rb0 = *(const float4*)(Wp);
    rb1 = *(const float4*)(Wp + M_DIM);
  }

  auto STAGE = [&](int buf) {
    if (isX) {
      const float v[8] = {ra0.x, ra0.y, ra0.z, ra0.w,
                          ra1.x, ra1.y, ra1.z, ra1.w};
      s16x8 hv, lv;
#pragma unroll
      for (int j = 0; j < 8; ++j) {
        const unsigned int hb = f2bf(v[j]);
        hv[j] = (short)hb;
        lv[j] = (short)f2bf(v[j] - bf2f(hb));
      }
      *(s16x8*)&Ah[buf][xr][xk] = hv;
      *(s16x8*)&Al[buf][xr][xk] = lv;
    } else {
      const float a[4] = {rb0.x, rb0.y, rb0.z, rb0.w};
      const float d[4] = {rb1.x, rb1.y, rb1.z, rb1.w};
#pragma unroll
      for (int i = 0; i < 4; ++i) {
        const unsigned int ha = f2bf(a[i]), hd = f2bf(d[i]);
        const unsigned int la = f2bf(a[i] - bf2f(ha));
        const unsigned int ld = f2bf(d[i] - bf2f(hd));
        *(unsigned int*)&Bh[buf][wc + i][wk] = ha | (hd << 16);
        *(unsigned int*)&Bl[buf][wc + i][wk] = la | (ld << 16);
      }
    }
  };

  STAGE(0);
  __syncthreads();

  for (int it = 0; it < NSTEP; ++it) {
    const int cur = it & 1;
    if (it + 1 < NSTEP) {
      const int k0 = (it + 1) * KSTEP;
      if (isX) {
        ra0 = *(const float4*)(Xp + k0);
        ra1 = *(const float4*)(Xp + k0 + 4);
      } else {
        rb0 = *(const float4*)(Wp + (size_t)k0 * M_DIM);
        rb1 = *(const float4*)(Wp + (size_t)(k0 + 1) * M_DIM);
      }
    }
    const s16x8 ah = *(const s16x8*)&Ah[cur][m0 + fr][fq];
    const s16x8 al = *(const s16x8*)&Al[cur][m0 + fr][fq];
    const s16x8 bh = *(const s16x8*)&Bh[cur][n0 + fr][fq];
    const s16x8 bl = *(const s16x8*)&Bl[cur][n0 + fr][fq];
    acc = __builtin_amdgcn_mfma_f32_16x16x32_bf16(ah, bh, acc, 0, 0, 0);
    acc = __builtin_amdgcn_mfma_f32_16x16x32_bf16(al, bh, acc, 0, 0, 0);
    acc = __builtin_amdgcn_mfma_f32_16x16x32_bf16(ah, bl, acc, 0, 0, 0);
    if (it + 1 < NSTEP) STAGE(cur ^ 1);
    __syncthreads();
  }

  // store with relu; C layout (verified): col = lane&15, row = (lane>>4)*4+r
  const int r0 = (lane >> 4) * 4;
#pragma unroll
  for (int r = 0; r < 4; ++r)
    feat[(size_t)(bm + m0 + r0 + r) * M_DIM + bn + n0 + fr] =
        fmaxf(acc[r], 0.0f);
}

// ---------------------------------------------------------------------------
// Kernel 2: phi row-panels + mu/count (R8 structure, single feat input —
// relu already applied by gemm).
// grid = (17, C): panels 0..15 -> 32 rows x 512 cols; panel 16 -> mu/count.
// ---------------------------------------------------------------------------
__global__ __launch_bounds__(256, 4) void phi_mu_kernel(
    const float* __restrict__ feat, const int* __restrict__ counts,
    const int* __restrict__ idx, float* __restrict__ phi,
    float* __restrict__ mu, float* __restrict__ cnt_out) {
  const int c = blockIdx.y;
  const int n = counts[c];
  const int* __restrict__ id = idx + c * B_N;
  const int t = threadIdx.x;

  if (blockIdx.x == 16) {  // ---- mu / count path ----
    float2 acc = make_float2(0.f, 0.f);
    for (int s = 0; s < n; ++s) {
      const float2 q = *(const float2*)&feat[(size_t)id[s] * M_DIM + t * 2];
      acc.x += q.x;
      acc.y += q.y;
    }
    *(float2*)&mu[(size_t)c * M_DIM + t * 2] = acc;
    if (t == 0) cnt_out[c] = (float)n;
    return;
  }

  // ---- phi row-panel path: rows 32*px..+32, all 512 cols ----
  const int px = (int)blockIdx.x;      // 0..15
  const int tr = t >> 6;               // row group 0..3 (x8 rows)
  const int tc = t & 63;               // cols tc*4 and 256+tc*4

  __shared__ float F[16][M_DIM];

  float acc[8][8] = {};

  for (int s0 = 0; s0 < n; s0 += 16) {
    const int chunk  = min(16, n - s0);
    if (s0) __syncthreads();           // protect F before overwrite
    const int nslots = chunk << 7;     // chunk * 128 float4 per row
    for (int v = t; v < nslots; v += 256) {
      const int sl = v >> 7;
      const int fp = (v & 127) << 2;
      *(float4*)&F[sl][fp] =
          *(const float4*)&feat[(size_t)id[s0 + sl] * M_DIM + fp];
    }
    __syncthreads();
    for (int sl = 0; sl < chunk; ++sl) {
      const float4 a0 = *(const float4*)&F[sl][px * 32 + tr * 8];      // bcast
      const float4 a1 = *(const float4*)&F[sl][px * 32 + tr * 8 + 4];  // bcast
      const float4 b0 = *(const float4*)&F[sl][tc * 4];        // contiguous
      const float4 b1 = *(const float4*)&F[sl][256 + tc * 4];  // contiguous
      const float av[8] = {a0.x, a0.y, a0.z, a0.w, a1.x, a1.y, a1.z, a1.w};
      const float bv[8] = {b0.x, b0.y, b0.z, b0.w, b1.x, b1.y, b1.z, b1.w};
#pragma unroll
      for (int r = 0; r < 8; ++r)
#pragma unroll
        for (int q = 0; q < 8; ++q)
          acc[r][q] += av[r] * bv[q];
    }
  }

  float* __restrict__ out = phi + (size_t)c * M_DIM * M_DIM;
#pragma unroll
  for (int r = 0; r < 8; ++r) {
    const size_t row = (size_t)(px * 32 + tr * 8 + r) * M_DIM;
    const f32x4 o0 = {acc[r][0], acc[r][1], acc[r][2], acc[r][3]};
    const f32x4 o1 = {acc[r][4], acc[r][5], acc[r][6], acc[r][7]};
    __builtin_nontemporal_store(o0, (f32x4*)&out[row + tc * 4]);
    __builtin_nontemporal_store(o1, (f32x4*)&out[row + 256 + tc * 4]);
  }
}

// ---------------------------------------------------------------------------
extern "C" void kernel_launch(void* const* d_in, const int* in_sizes, int n_in,
                              void* d_out, int out_size, void* d_ws,
                              size_t ws_size, hipStream_t stream) {
  const float* X      = (const float*)d_in[0];
  const float* W      = (const float*)d_in[1];
  const int*   labels = (const int*)d_in[2];

  float* out = (float*)d_out;
  float* phi = out;                                // C*M*M
  float* mu  = out + (size_t)C_N * M_DIM * M_DIM;  // C*M
  float* cnt = mu + (size_t)C_N * M_DIM;           // C

  float* feat   = (float*)d_ws;                    // B*M fp32 = 2 MB
  int*   counts = (int*)((char*)d_ws + (size_t)B_N * M_DIM * sizeof(float));
  int*   idx    = counts + 128;                    // C*B ints

  hipLaunchKernelGGL(gemm_index_kernel, dim3(NGEMM + NIDX), dim3(256), 0,
                     stream, X, W, labels, feat, counts, idx);
  hipLaunchKernelGGL(phi_mu_kernel, dim3(17, C_N), dim3(256), 0, stream,
                     feat, counts, idx, phi, mu, cnt);
}